// Round 7
// baseline (4969.353 us; speedup 1.0000x reference)
//
#include <hip/hip_runtime.h>

#define BSZ 64
#define SLEN 32
#define HID 128
#define VOC 96
#define DEPTH 500
#define TPB 128             // 2 waves per block (one block per batch row)
#define EPSV 1e-6f
#define CHK 36              // padded chunk stride in floats (32 data + 4 pad)

typedef __attribute__((ext_vector_type(2))) float f32x2;

#if defined(__has_builtin)
#if __has_builtin(__builtin_elementwise_fma)
#define VFMA(a, b, c) __builtin_elementwise_fma((a), (b), (c))
#endif
#endif
#ifndef VFMA
__device__ __forceinline__ f32x2 vfma_(f32x2 a, f32x2 b, f32x2 c) {
    f32x2 r; r.x = fmaf(a.x, b.x, c.x); r.y = fmaf(a.y, b.y, c.y); return r;
}
#define VFMA(a, b, c) vfma_((a), (b), (c))
#endif

__device__ __forceinline__ float rsq_fast(float x) {
    float r; asm("v_rsq_f32 %0, %1" : "=v"(r) : "v"(x)); return r;
}

// 4-lane combine: xor1 + xor2 via DPP quad_perm (pure VALU, stays in the quad)
template <int CTRL>
__device__ __forceinline__ float qperm(float v) {
    return __int_as_float(__builtin_amdgcn_update_dpp(
        0, __float_as_int(v), CTRL, 0xF, 0xF, true));
}
#define BFLY4(v)                                                               \
    v += qperm<0xB1>(v);  /* xor1 */                                           \
    v += qperm<0x4E>(v);  /* xor2 */

__global__ __launch_bounds__(TPB, 1) void rnn_char_lm(
    const int* __restrict__ chars, const float* __restrict__ hidden,
    const float* __restrict__ embed_w, const float* __restrict__ W_g,
    const float* __restrict__ b_g, const float* __restrict__ pre_s,
    const float* __restrict__ post_s, const float* __restrict__ rw_g,
    const float* __restrict__ rb_g, float* __restrict__ out)
{
    __shared__ __align__(16) float hbuf[2][4 * CHK];  // padded chunked h, dbuf
    __shared__ float rwT[HID * VOC];                  // readout_w transposed [k][v]

    const int b = blockIdx.x;
    const int tid = threadIdx.x;
    const int wv = tid >> 6;          // wave: cols [64*wv, 64*wv+64)
    const int lane = tid & 63;
    const int g = lane >> 2;          // col-group: 4 consecutive cols (16 groups)
    const int ch = lane & 3;          // k-chunk: 32 k-values

    const int col0 = 64 * wv + 4 * g; // lane's 4 cols: col0..col0+3
    // chunk layout: h[32*C + m] at LDS float index CHK*C + m
    const int widx = CHK * (col0 >> 5) + (col0 & 31);
    const int rbase = CHK * ch;       // lane's read chunk base (float idx)

    // one-time: stage readout_w transposed into LDS (round-2 proven)
    for (int e = tid; e < VOC * HID; e += TPB) {
        int v = e >> 7;
        int k = e & (HID - 1);
        rwT[k * VOC + v] = rw_g[e];
    }

    // one-time: W' = pre_scale[k]*W[k][col0+c], packed over k-pairs. 128 VGPRs.
    f32x2 W2[4][16];
#pragma unroll
    for (int q = 0; q < 16; ++q) {
        int k0 = 32 * ch + 2 * q;
        float p0 = pre_s[k0], p1 = pre_s[k0 + 1];
#pragma unroll
        for (int c = 0; c < 4; ++c) {
            f32x2 t;
            t.x = p0 * W_g[k0 * HID + col0 + c];
            t.y = p1 * W_g[(k0 + 1) * HID + col0 + c];
            W2[c][q] = t;
        }
    }
    const float4 bv  = *(const float4*)&b_g[col0];
    const float4 psv = *(const float4*)&post_s[col0];
    const float rbv = (tid < VOC) ? rb_g[tid] : 0.0f;

    // h for lane's 4 cols (replicated across the 4 ch-lanes of group g)
    float4 hc = *(const float4*)&hidden[b * HID + col0];

    if (ch == 0) *(float4*)&hbuf[0][widx] = hc;   // stage initial h
    __syncthreads();

// one recurrent iteration at compile-time read-parity P (reads P, writes P^1)
#define ITER(P)                                                                \
    {                                                                          \
        const float4* rb = (const float4*)&hbuf[P][rbase];                     \
        float4 x0 = rb[0], x1 = rb[1], x2 = rb[2], x3 = rb[3];                 \
        float4 x4 = rb[4], x5 = rb[5], x6 = rb[6], x7 = rb[7];                 \
        f32x2 a0 = {0,0}, a1 = {0,0}, a2 = {0,0}, a3 = {0,0}, s = {0,0};       \
        _Pragma("unroll")                                                      \
        for (int q = 0; q < 16; ++q) {                                         \
            const float4 xq = (q < 2) ? x0 : (q < 4) ? x1 : (q < 6) ? x2 :     \
                              (q < 8) ? x3 : (q < 10) ? x4 : (q < 12) ? x5 :   \
                              (q < 14) ? x6 : x7;                              \
            f32x2 hv;                                                          \
            hv.x = (q & 1) ? xq.z : xq.x;                                      \
            hv.y = (q & 1) ? xq.w : xq.y;                                      \
            s  = VFMA(hv, hv, s);                                              \
            a0 = VFMA(hv, W2[0][q], a0);                                       \
            a1 = VFMA(hv, W2[1][q], a1);                                       \
            a2 = VFMA(hv, W2[2][q], a2);                                       \
            a3 = VFMA(hv, W2[3][q], a3);                                       \
        }                                                                      \
        float y0 = a0.x + a0.y, y1 = a1.x + a1.y;                              \
        float y2 = a2.x + a2.y, y3 = a3.x + a3.y;                              \
        float ssl = s.x + s.y;                                                 \
        BFLY4(y0) BFLY4(y1) BFLY4(y2) BFLY4(y3) BFLY4(ssl)                     \
        const float rn = rsq_fast(fmaf(ssl, 1.0f / HID, EPSV));                \
        hc.x += fmaxf(fmaf(y0, rn, ev.x), 0.0f);                               \
        hc.y += fmaxf(fmaf(y1, rn, ev.y), 0.0f);                               \
        hc.z += fmaxf(fmaf(y2, rn, ev.z), 0.0f);                               \
        hc.w += fmaxf(fmaf(y3, rn, ev.w), 0.0f);                               \
        if (ch == 0) *(float4*)&hbuf[P ^ 1][widx] = hc;                        \
        __syncthreads();                                                       \
    }

    for (int t = 0; t < SLEN; ++t) {
        const int c = chars[b * SLEN + t];
        const float4 er = *(const float4*)&embed_w[c * HID + col0];
        float4 ev;
        ev.x = er.x + bv.x; ev.y = er.y + bv.y;
        ev.z = er.z + bv.z; ev.w = er.w + bv.w;

        for (int it = 0; it < DEPTH / 2; ++it) {
            ITER(0)
            ITER(1)
        }
        // after 500 iters, current h sits in hbuf[0]; parity invariant per t.

        // ---- epilogue: post-norm (replaces h) + readout ----
        {
            const float4* rb = (const float4*)&hbuf[0][rbase];
            f32x2 s = {0, 0};
#pragma unroll
            for (int q8 = 0; q8 < 8; ++q8) {
                float4 x = rb[q8];
                f32x2 hv;
                hv.x = x.x; hv.y = x.y; s = VFMA(hv, hv, s);
                hv.x = x.z; hv.y = x.w; s = VFMA(hv, hv, s);
            }
            float ssl = s.x + s.y;
            BFLY4(ssl)
            const float rnp = 1.0f / sqrtf(ssl * (1.0f / HID) + EPSV);
            hc.x *= rnp * psv.x; hc.y *= rnp * psv.y;
            hc.z *= rnp * psv.z; hc.w *= rnp * psv.w;
            __syncthreads();                         // all ss-reads of hbuf[0] done
            if (ch == 0) *(float4*)&hbuf[0][widx] = hc;  // hpost, chunked layout
            __syncthreads();                         // visible to readout + next t
        }

        if (tid < VOC) {
            float acc0 = 0.0f, acc1 = 0.0f;
#pragma unroll
            for (int C = 0; C < 4; ++C) {
#pragma unroll
                for (int m4 = 0; m4 < 8; ++m4) {
                    const float4 x = *(const float4*)&hbuf[0][CHK * C + 4 * m4];
                    const int k = 32 * C + 4 * m4;
                    acc0 = fmaf(x.x, rwT[(k + 0) * VOC + tid], acc0);
                    acc1 = fmaf(x.y, rwT[(k + 1) * VOC + tid], acc1);
                    acc0 = fmaf(x.z, rwT[(k + 2) * VOC + tid], acc0);
                    acc1 = fmaf(x.w, rwT[(k + 3) * VOC + tid], acc1);
                }
            }
            out[(b * SLEN + t) * VOC + tid] = acc0 + acc1 + rbv;
        }
        // next t's ITER(0) reads hbuf[0] (reads only; first write goes to
        // hbuf[1], gated by its own end-of-ITER barrier) -> no extra barrier.
    }

    if (ch == 0)
        *(float4*)&out[BSZ * SLEN * VOC + b * HID + col0] = hc;

#undef ITER
}

extern "C" void kernel_launch(void* const* d_in, const int* in_sizes, int n_in,
                              void* d_out, int out_size, void* d_ws, size_t ws_size,
                              hipStream_t stream)
{
    const int* chars      = (const int*)d_in[0];
    const float* hidden   = (const float*)d_in[1];
    const float* embed_w  = (const float*)d_in[2];
    const float* W_g      = (const float*)d_in[3];
    const float* b_g      = (const float*)d_in[4];
    const float* pre_s    = (const float*)d_in[5];
    const float* post_s   = (const float*)d_in[6];
    const float* rw_g     = (const float*)d_in[7];
    const float* rb_g     = (const float*)d_in[8];
    float* out            = (float*)d_out;

    rnn_char_lm<<<dim3(BSZ), dim3(TPB), 0, stream>>>(
        chars, hidden, embed_w, W_g, b_g, pre_s, post_s, rw_g, rb_g, out);
}

// Round 8
// 4001.522 us; speedup vs baseline: 1.2419x; 1.2419x over previous
//
#include <hip/hip_runtime.h>

#define BSZ 64
#define SLEN 32
#define HID 128
#define VOC 96
#define DEPTH 500
#define TPB 256
#define EPSV 1e-6f
#define PAD 20              // floats per 16-float h-chunk (16 data + 4 pad)

typedef __attribute__((ext_vector_type(2))) float f32x2;

#if defined(__has_builtin)
#if __has_builtin(__builtin_elementwise_fma)
#define VFMA(a, b, c) __builtin_elementwise_fma((a), (b), (c))
#endif
#endif
#ifndef VFMA
__device__ __forceinline__ f32x2 vfma_(f32x2 a, f32x2 b, f32x2 c) {
    f32x2 r; r.x = fmaf(a.x, b.x, c.x); r.y = fmaf(a.y, b.y, c.y); return r;
}
#define VFMA(a, b, c) vfma_((a), (b), (c))
#endif

__device__ __forceinline__ float rsq_fast(float x) {
    float r; asm("v_rsq_f32 %0, %1" : "=v"(r) : "v"(x)); return r;
}

// DPP helpers (ctrl must be a compile-time constant).
// 0xB1 = quad_perm xor1, 0x4E = quad_perm xor2, 0x141 = row_half_mirror.
template <int CTRL>
__device__ __forceinline__ float qperm(float v) {
    return __int_as_float(__builtin_amdgcn_update_dpp(
        0, __float_as_int(v), CTRL, 0xF, 0xF, true));
}
// 8-lane reduction, pure VALU: after xor1+xor2 all quad lanes hold the quad
// sum; row_half_mirror (l -> 7-l within each 8-lane half-row) always sources
// the OTHER quad -> adding it completes the 8-lane sum (bit-identical to xor4).
#define BFLY8(v)                                                               \
    v += qperm<0xB1>(v);   /* xor1 */                                          \
    v += qperm<0x4E>(v);   /* xor2 */                                          \
    v += qperm<0x141>(v);  /* cross-quad via row_half_mirror */

__global__ __launch_bounds__(TPB, 1) void rnn_char_lm(
    const int* __restrict__ chars, const float* __restrict__ hidden,
    const float* __restrict__ embed_w, const float* __restrict__ W_g,
    const float* __restrict__ b_g, const float* __restrict__ pre_s,
    const float* __restrict__ post_s, const float* __restrict__ rw_g,
    const float* __restrict__ rb_g, float* __restrict__ out)
{
    __shared__ __align__(16) float hbuf[2][8 * PAD];  // padded chunked h, dbuf
    __shared__ float rwT[HID * VOC];                  // readout_w transposed [k][v]

    const int b = blockIdx.x;
    const int tid = threadIdx.x;
    const int w = tid >> 6;
    const int lane = tid & 63;
    const int g = lane >> 3;          // col-group: 4 consecutive cols
    const int ch = lane & 7;          // k-chunk: 16 k-values

    const int col0 = 32 * w + 4 * g;  // lane's 4 cols: col0..col0+3
    // padded write index for col0 (chunk layout: h[16C+m] at 20C+m)
    const int widx = PAD * (col0 >> 4) + (col0 & 15);
    const int rbase = PAD * ch;       // lane's read chunk base (float idx)

    // one-time: stage readout_w transposed into LDS (round-2 proven)
    for (int e = tid; e < VOC * HID; e += TPB) {
        int v = e >> 7;
        int k = e & (HID - 1);
        rwT[k * VOC + v] = rw_g[e];
    }

    // one-time: W' = pre_scale[k]*W[k][col0+c], packed over k-pairs. 64 VGPRs.
    f32x2 W2[4][8];
#pragma unroll
    for (int q = 0; q < 8; ++q) {
        int k0 = 16 * ch + 2 * q;
        float p0 = pre_s[k0], p1 = pre_s[k0 + 1];
#pragma unroll
        for (int c = 0; c < 4; ++c) {
            f32x2 t;
            t.x = p0 * W_g[k0 * HID + col0 + c];
            t.y = p1 * W_g[(k0 + 1) * HID + col0 + c];
            W2[c][q] = t;
        }
    }
    const float4 bv  = *(const float4*)&b_g[col0];
    const float4 psv = *(const float4*)&post_s[col0];
    const float rbv = (tid < VOC) ? rb_g[tid] : 0.0f;

    // h for lane's 4 cols (replicated across the 8 ch-lanes of group g)
    float4 hc = *(const float4*)&hidden[b * HID + col0];

    if (ch == 0) *(float4*)&hbuf[0][widx] = hc;   // stage initial h
    __syncthreads();

// one recurrent iteration at compile-time read-parity P (reads P, writes P^1)
#define ITER(P)                                                                \
    {                                                                          \
        const float4* rb = (const float4*)&hbuf[P][rbase];                     \
        float4 x0 = rb[0], x1 = rb[1], x2 = rb[2], x3 = rb[3];                 \
        f32x2 a0 = {0,0}, a1 = {0,0}, a2 = {0,0}, a3 = {0,0}, s = {0,0};       \
        _Pragma("unroll")                                                      \
        for (int q = 0; q < 8; ++q) {                                          \
            const float4 xq = (q < 2) ? x0 : (q < 4) ? x1 : (q < 6) ? x2 : x3; \
            f32x2 hv;                                                          \
            hv.x = (q & 1) ? xq.z : xq.x;                                      \
            hv.y = (q & 1) ? xq.w : xq.y;                                      \
            s  = VFMA(hv, hv, s);                                              \
            a0 = VFMA(hv, W2[0][q], a0);                                       \
            a1 = VFMA(hv, W2[1][q], a1);                                       \
            a2 = VFMA(hv, W2[2][q], a2);                                       \
            a3 = VFMA(hv, W2[3][q], a3);                                       \
        }                                                                      \
        float y0 = a0.x + a0.y, y1 = a1.x + a1.y;                              \
        float y2 = a2.x + a2.y, y3 = a3.x + a3.y;                              \
        float ssl = s.x + s.y;                                                 \
        BFLY8(y0) BFLY8(y1) BFLY8(y2) BFLY8(y3) BFLY8(ssl)                     \
        const float rn = rsq_fast(fmaf(ssl, 1.0f / HID, EPSV));                \
        hc.x += fmaxf(fmaf(y0, rn, ev.x), 0.0f);                               \
        hc.y += fmaxf(fmaf(y1, rn, ev.y), 0.0f);                               \
        hc.z += fmaxf(fmaf(y2, rn, ev.z), 0.0f);                               \
        hc.w += fmaxf(fmaf(y3, rn, ev.w), 0.0f);                               \
        if (ch == 0) *(float4*)&hbuf[P ^ 1][widx] = hc;                        \
        __syncthreads();                                                       \
    }

    for (int t = 0; t < SLEN; ++t) {
        const int c = chars[b * SLEN + t];
        const float4 er = *(const float4*)&embed_w[c * HID + col0];
        float4 ev;
        ev.x = er.x + bv.x; ev.y = er.y + bv.y;
        ev.z = er.z + bv.z; ev.w = er.w + bv.w;

        for (int it = 0; it < DEPTH / 2; ++it) {
            ITER(0)
            ITER(1)
        }
        // after 500 iters, current h sits in hbuf[0]; parity invariant per t.

        // ---- epilogue: post-norm (replaces h) + readout ----
        {
            // sumsq from hbuf[0] via the same chunk reads + butterfly
            const float4* rb = (const float4*)&hbuf[0][rbase];
            float4 x0 = rb[0], x1 = rb[1], x2 = rb[2], x3 = rb[3];
            f32x2 s = {0, 0};
            f32x2 hv;
            hv.x = x0.x; hv.y = x0.y; s = VFMA(hv, hv, s);
            hv.x = x0.z; hv.y = x0.w; s = VFMA(hv, hv, s);
            hv.x = x1.x; hv.y = x1.y; s = VFMA(hv, hv, s);
            hv.x = x1.z; hv.y = x1.w; s = VFMA(hv, hv, s);
            hv.x = x2.x; hv.y = x2.y; s = VFMA(hv, hv, s);
            hv.x = x2.z; hv.y = x2.w; s = VFMA(hv, hv, s);
            hv.x = x3.x; hv.y = x3.y; s = VFMA(hv, hv, s);
            hv.x = x3.z; hv.y = x3.w; s = VFMA(hv, hv, s);
            float ssl = s.x + s.y;
            BFLY8(ssl)
            const float rnp = 1.0f / sqrtf(ssl * (1.0f / HID) + EPSV);
            hc.x *= rnp * psv.x; hc.y *= rnp * psv.y;
            hc.z *= rnp * psv.z; hc.w *= rnp * psv.w;
            __syncthreads();                         // all ss-reads of hbuf[0] done
            if (ch == 0) *(float4*)&hbuf[0][widx] = hc;  // hpost, padded layout
            __syncthreads();                         // visible to readout + next t
        }

        if (tid < VOC) {
            float acc0 = 0.0f, acc1 = 0.0f;
#pragma unroll
            for (int C = 0; C < 8; ++C) {
#pragma unroll
                for (int m4 = 0; m4 < 4; ++m4) {
                    const float4 x = *(const float4*)&hbuf[0][PAD * C + 4 * m4];
                    const int k = 16 * C + 4 * m4;
                    acc0 = fmaf(x.x, rwT[(k + 0) * VOC + tid], acc0);
                    acc1 = fmaf(x.y, rwT[(k + 1) * VOC + tid], acc1);
                    acc0 = fmaf(x.z, rwT[(k + 2) * VOC + tid], acc0);
                    acc1 = fmaf(x.w, rwT[(k + 3) * VOC + tid], acc1);
                }
            }
            out[(b * SLEN + t) * VOC + tid] = acc0 + acc1 + rbv;
        }
        // waves 2-3 run ahead into next t's ITER(0): reads hbuf[0] (no write
        // conflict; first write goes to hbuf[1], gated by its own barrier).
    }

    if (ch == 0)
        *(float4*)&out[BSZ * SLEN * VOC + b * HID + col0] = hc;

#undef ITER
}

extern "C" void kernel_launch(void* const* d_in, const int* in_sizes, int n_in,
                              void* d_out, int out_size, void* d_ws, size_t ws_size,
                              hipStream_t stream)
{
    const int* chars      = (const int*)d_in[0];
    const float* hidden   = (const float*)d_in[1];
    const float* embed_w  = (const float*)d_in[2];
    const float* W_g      = (const float*)d_in[3];
    const float* b_g      = (const float*)d_in[4];
    const float* pre_s    = (const float*)d_in[5];
    const float* post_s   = (const float*)d_in[6];
    const float* rw_g     = (const float*)d_in[7];
    const float* rb_g     = (const float*)d_in[8];
    float* out            = (float*)d_out;

    rnn_char_lm<<<dim3(BSZ), dim3(TPB), 0, stream>>>(
        chars, hidden, embed_w, W_g, b_g, pre_s, post_s, rw_g, rb_g, out);
}